// Round 14
// baseline (143.520 us; speedup 1.0000x reference)
//
#include <hip/hip_runtime.h>
#include <stdint.h>

#define N_NODES 100000
#define KNBR 16
#define ALPHA 0.2f

typedef __attribute__((ext_vector_type(8))) short bf16x8;
typedef __attribute__((ext_vector_type(4))) float f32x4;
typedef __attribute__((ext_vector_type(4))) unsigned int u32x4;
typedef unsigned short u16;
typedef unsigned int u32;
typedef unsigned char u8;

static __device__ __forceinline__ u16 f2bf(float f) {
  u32 u = __builtin_bit_cast(u32, f);
  u += 0x7fffu + ((u >> 16) & 1u);   // round-to-nearest-even
  return (u16)(u >> 16);
}

// ---- Kernel 1: W -> Wb in MFMA B-fragment order ----
// frag(ks, ct): lane l, elem i = W[ks*32 + (l>>4)*8 + i][ct*16 + (l&15)]
__global__ __launch_bounds__(256) void prep_w_kernel(const float* __restrict__ W,
                                                     u16* __restrict__ Wb) {
  const int t = blockIdx.x * 256 + threadIdx.x;  // 0..8191
  const int l = t & 63;
  const int ct = (t >> 6) & 15;
  const int ks = t >> 10;
  const int colbase = ct * 16 + (l & 15);
  const int k0 = ks * 32 + (l >> 4) * 8;
  u32 wq[4];
#pragma unroll
  for (int q = 0; q < 4; ++q) {
    const u16 b0 = f2bf(W[(k0 + 2 * q) * 256 + colbase]);
    const u16 b1 = f2bf(W[(k0 + 2 * q + 1) * 256 + colbase]);
    wq[q] = (u32)b0 | ((u32)b1 << 16);
  }
  u32x4 o = {wq[0], wq[1], wq[2], wq[3]};
  *(u32x4*)(Wb + (size_t)t * 8) = o;
}

// ---- Kernel 2: BARRIER-FREE GEMM + int8 quant (R13 structure, unchanged) ----
// Wave-independent: 16 rows x 256 cols per wave, A direct from global,
// cvt_pk in-register, B from L2-resident Wb. No LDS, no __syncthreads.
// Yq rows stored byte-PERMUTED: byte p = g*64 + l15*4 + c4 holds column
// (g*4+c4)*16 + l15. Gather decodes positions accordingly.
__global__ __launch_bounds__(256, 3) void gemm_kernel(const float* __restrict__ h,
                                                      const u16* __restrict__ Wb,
                                                      u8* __restrict__ Yq,
                                                      float* __restrict__ scale) {
  const int tid = threadIdx.x;
  const int l = tid & 63, wv = tid >> 6;
  const int l15 = l & 15, lg = l >> 4;
  const int rowb = blockIdx.x * 64 + wv * 16;          // wave's 16 rows
  int arow = rowb + l15;
  if (arow >= N_NODES) arow = N_NODES - 1;             // clamp (stores guarded)
  const float* hrow = h + (size_t)arow * 256;
  const u32x4* wb = (const u32x4*)Wb;

  f32x4 acc[16] = {};                                  // c-tiles 0..15
#pragma unroll
  for (int ks = 0; ks < 8; ++ks) {
    const f32x4 a0 = __builtin_nontemporal_load((const f32x4*)(hrow + ks * 32 + lg * 8));
    const f32x4 a1 = __builtin_nontemporal_load((const f32x4*)(hrow + ks * 32 + lg * 8 + 4));
    u32 p0, p1, p2, p3;
    asm("v_cvt_pk_bf16_f32 %0, %1, %2" : "=v"(p0) : "v"(a0[0]), "v"(a0[1]));
    asm("v_cvt_pk_bf16_f32 %0, %1, %2" : "=v"(p1) : "v"(a0[2]), "v"(a0[3]));
    asm("v_cvt_pk_bf16_f32 %0, %1, %2" : "=v"(p2) : "v"(a1[0]), "v"(a1[1]));
    asm("v_cvt_pk_bf16_f32 %0, %1, %2" : "=v"(p3) : "v"(a1[2]), "v"(a1[3]));
    u32x4 au = {p0, p1, p2, p3};
    const bf16x8 a = __builtin_bit_cast(bf16x8, au);
#pragma unroll
    for (int c = 0; c < 16; ++c) {
      const u32x4 bw = wb[(size_t)(ks * 16 + c) * 64 + l];   // plain load: keep L2-hot
      const bf16x8 b = __builtin_bit_cast(bf16x8, bw);
      acc[c] = __builtin_amdgcn_mfma_f32_16x16x32_bf16(a, b, acc[c], 0, 0, 0);
    }
  }

  // epilogue: per j (row = rowb + lg*4 + j): rowmax -> scale -> quant -> store
#pragma unroll
  for (int j = 0; j < 4; ++j) {
    float m = 0.f;
#pragma unroll
    for (int c = 0; c < 16; ++c) m = fmaxf(m, fabsf(acc[c][j]));
    m = fmaxf(m, __shfl_xor(m, 1)); m = fmaxf(m, __shfl_xor(m, 2));
    m = fmaxf(m, __shfl_xor(m, 4)); m = fmaxf(m, __shfl_xor(m, 8));
    m = fmaxf(m, 1e-20f);
    const float invj = 127.0f / m;

    const int r = rowb + lg * 4 + j;
    if (r < N_NODES) {
      if (l15 == 0) scale[r] = m * (1.0f / 127.0f);
      u8* yr = Yq + (size_t)r * 256 + l15 * 4;
#pragma unroll
      for (int g = 0; g < 4; ++g) {            // pack 4 c-tiles per u32
        u32 pk = 0;
#pragma unroll
        for (int c4 = 0; c4 < 4; ++c4) {
          float t = fmaf(acc[g * 4 + c4][j], invj, 128.5f);
          t = fminf(255.f, fmaxf(1.f, t));
          pk |= ((u32)(u8)(u32)t) << (8 * c4);
        }
        __builtin_nontemporal_store(pk, (u32*)(yr + g * 64));
      }
    }
  }
}

// ---- Kernel 3: gather-mean (int8 Y-space) + leaky + L2-normalize ----
// R5/R11 load structure (proven 69.5 us floor). FIX vs R13: output store
// honors the Yq row permutation — lane's byte c4 (at row byte lane*4+c4)
// holds column (g*4+c4)*16 + l15 where g=lane>>4, l15=lane&15.
__global__ __launch_bounds__(256) void gather_kernel(const u8* __restrict__ Yq,
                                                     const float* __restrict__ scale,
                                                     const int* __restrict__ nbr,
                                                     float* __restrict__ out) {
  const int tid = threadIdx.x;
  const int lane = tid & 63, wv = tid >> 6;
  const int node = __builtin_amdgcn_readfirstlane(blockIdx.x * 4 + wv);

  const int il = nbr[node * KNBR + (lane & 15)];
  const float vscale = scale[il];
  const float sself = scale[node];
  const u32* yb = (const u32*)Yq;

  u32 v[17];
  v[0] = yb[(size_t)node * 64 + lane];
#pragma unroll
  for (int j = 0; j < 16; ++j) {
    const int r = __builtin_amdgcn_readlane(il, j);
    v[j + 1] = yb[(size_t)r * 64 + lane];
  }

  float a0, a1, a2, a3, S = sself;
  {
    float f0, f1, f2, f3;
    asm("v_cvt_f32_ubyte0 %0, %1" : "=v"(f0) : "v"(v[0]));
    asm("v_cvt_f32_ubyte1 %0, %1" : "=v"(f1) : "v"(v[0]));
    asm("v_cvt_f32_ubyte2 %0, %1" : "=v"(f2) : "v"(v[0]));
    asm("v_cvt_f32_ubyte3 %0, %1" : "=v"(f3) : "v"(v[0]));
    a0 = sself * f0; a1 = sself * f1; a2 = sself * f2; a3 = sself * f3;
  }
#pragma unroll
  for (int j = 0; j < 16; ++j) {
    const float s = __builtin_bit_cast(
        float, __builtin_amdgcn_readlane(__builtin_bit_cast(int, vscale), j));
    float f0, f1, f2, f3;
    asm("v_cvt_f32_ubyte0 %0, %1" : "=v"(f0) : "v"(v[j + 1]));
    asm("v_cvt_f32_ubyte1 %0, %1" : "=v"(f1) : "v"(v[j + 1]));
    asm("v_cvt_f32_ubyte2 %0, %1" : "=v"(f2) : "v"(v[j + 1]));
    asm("v_cvt_f32_ubyte3 %0, %1" : "=v"(f3) : "v"(v[j + 1]));
    S += s;
    a0 = fmaf(s, f0, a0); a1 = fmaf(s, f1, a1);
    a2 = fmaf(s, f2, a2); a3 = fmaf(s, f3, a3);
  }
  const float sc = 1.0f / 17.0f, bias = 128.0f * S;
  a0 = (a0 - bias) * sc; a1 = (a1 - bias) * sc;
  a2 = (a2 - bias) * sc; a3 = (a3 - bias) * sc;
  a0 = (a0 >= 0.f) ? a0 : ALPHA * a0;
  a1 = (a1 >= 0.f) ? a1 : ALPHA * a1;
  a2 = (a2 >= 0.f) ? a2 : ALPHA * a2;
  a3 = (a3 >= 0.f) ? a3 : ALPHA * a3;

  float ss = a0 * a0 + a1 * a1 + a2 * a2 + a3 * a3;
  ss += __shfl_xor(ss, 1);  ss += __shfl_xor(ss, 2);
  ss += __shfl_xor(ss, 4);  ss += __shfl_xor(ss, 8);
  ss += __shfl_xor(ss, 16); ss += __shfl_xor(ss, 32);
  const float inv = 1.0f / fmaxf(sqrtf(ss), 1e-12f);

  // permutation-aware store: byte c4 -> column g*64 + c4*16 + l15
  const int g = lane >> 4, li = lane & 15;
  float* op = out + (size_t)node * 256 + g * 64 + li;
  __builtin_nontemporal_store(a0 * inv, op);
  __builtin_nontemporal_store(a1 * inv, op + 16);
  __builtin_nontemporal_store(a2 * inv, op + 32);
  __builtin_nontemporal_store(a3 * inv, op + 48);
}

extern "C" void kernel_launch(void* const* d_in, const int* in_sizes, int n_in,
                              void* d_out, int out_size, void* d_ws, size_t ws_size,
                              hipStream_t stream) {
  const float* h = (const float*)d_in[0];
  const int* nbr = (const int*)d_in[1];
  const float* W = (const float*)d_in[2];
  float* out = (float*)d_out;

  char* ws = (char*)d_ws;
  u16* Wb = (u16*)ws;                               // 128 KB fragment-ordered W
  float* scale = (float*)(ws + (1 << 17));          // ~400 KB f32 row scales
  u8* Yq = (u8*)(ws + (1 << 20));                   // 25.6 MB int8 Y (row-permuted)

  prep_w_kernel<<<32, 256, 0, stream>>>(W, Wb);
  gemm_kernel<<<(N_NODES + 63) / 64, 256, 0, stream>>>(h, Wb, Yq, scale);
  gather_kernel<<<N_NODES / 4, 256, 0, stream>>>(Yq, scale, nbr, out);
}